// Round 7
// baseline (1466.745 us; speedup 1.0000x reference)
//
#include <hip/hip_runtime.h>
#include <hip/hip_bf16.h>
#include <math.h>

typedef __attribute__((ext_vector_type(8))) short bf16x8;
typedef __attribute__((ext_vector_type(4))) float f32x4;
using bf16 = __hip_bfloat16;

constexpr int NN   = 2048;
constexpr int KO   = 8;
constexpr int IH   = 128, IW = 128;
constexpr int GS   = 50;
constexpr int HIDD = 256;
// rin: [enc 0..100 | zwl 100..103 | pzw 103..106 | zwhatl 106..156 | pzwhat 156..206 | hl 206..462 | h_r 462..718 | pad..768]
constexpr int RIN_LD = 768;
// tin: [g2 0..2500 | zw 2500..2503 | pzw 2503..2506 | zwhatl 2506..2556 | pzwhat 2556..2606 | hl 2606..2862 | h_r2 2862..3118 | pad..3136]
constexpr int TIN_LD = 3136;
constexpr int G1_LD  = 2560;
constexpr int GROWS  = 64;        // LDS-staged image rows (32 KB)

__device__ __forceinline__ float sigm(float x) { return 1.f/(1.f+expf(-x)); }

// ================= MFMA GEMM v5: 128x64 block, BK=64, wave tile 64x32 ==================
// C[N][M] = A[N][Kd] @ W[M][Kd]^T. 4 waves in 2x2: wy=row-half(64), wx=col-half(32).
// Fragment-major LDS: A slot ((row>>4)*2+h)*64 + part*16 + (row&15)  [16B units]
// -> every wave staging write and frag read is a contiguous 1KB row-group (conflict-free).
// MODE 1: bf16 out + relu + bias (enc).  MODE 2: rel-LSTM epilogue.  MODE 3: tem-LSTM epilogue.
template<int MODE>
__global__ __launch_bounds__(256) void mfma_gemm(
    const bf16* __restrict__ A, int lda, int Kd,
    const bf16* __restrict__ Wt, int ldw, int M,
    const float* __restrict__ b1,
    const float* __restrict__ bint,
    void* __restrict__ Cout, int ldc,
    float* __restrict__ c_r, float* __restrict__ h_out,
    bf16* __restrict__ rin_next, bf16* __restrict__ tin_,
    float* __restrict__ out_htemp, int kstep)
{
    constexpr int SHBYTES = (MODE == 1) ? 24576 : 34816;
    __shared__ __align__(16) char shraw[SHBYTES];
    bf16x8* AS = (bf16x8*)shraw;          // 1024 slots (16 KB): 8 rowgroups x 2 h x 64
    bf16x8* BS = AS + 1024;               // 512 slots (8 KB):   4 colgroups x 2 h x 64
    float*  Gt = (float*)shraw;           // MODE 2/3 epilogue: 128 rows x stride 68

    const int tid  = threadIdx.x;
    const int n0   = blockIdx.y*128;
    const int m0   = blockIdx.x*64;
    const int wave = tid>>6, lane = tid&63;
    const int wy   = wave>>1, wx = wave&1;

    const int row  = tid>>2, part = tid&3;
    const bf16* Ap0 = A + (size_t)(n0+row)*lda      + part*8;
    const bf16* Ap1 = A + (size_t)(n0+row+64)*lda   + part*8;
    const int   wm  = m0 + row;
    const bool  wok = wm < M;
    const bf16* Wp  = Wt + (size_t)(wok ? wm : 0)*ldw + part*8;
    // LDS slots (16B units)
    const int aBase = (row>>4)*128 + part*16 + (row&15);   // + rb*512 + h*64
    const int bBase = aBase;                               // same formula for B (64 rows)

    f32x4 acc[4][2] = {};
    const bf16x8 z8 = {};
    bf16x8 pa[2][2], pb[2];
    #pragma unroll
    for (int h=0;h<2;h++) {
        pa[0][h] = *(const bf16x8*)(Ap0 + h*32);
        pa[1][h] = *(const bf16x8*)(Ap1 + h*32);
        pb[h]    = *(const bf16x8*)(Wp  + h*32);
    }

    for (int k0 = 0; k0 < Kd; k0 += 64) {
        __syncthreads();
        #pragma unroll
        for (int h=0;h<2;h++) {
            AS[aBase +       h*64] = pa[0][h];
            AS[aBase + 512 + h*64] = pa[1][h];
            BS[bBase +       h*64] = wok ? pb[h] : z8;
        }
        __syncthreads();
        if (k0 + 64 < Kd) {
            #pragma unroll
            for (int h=0;h<2;h++) {
                pa[0][h] = *(const bf16x8*)(Ap0 + k0 + 64 + h*32);
                pa[1][h] = *(const bf16x8*)(Ap1 + k0 + 64 + h*32);
                pb[h]    = *(const bf16x8*)(Wp  + k0 + 64 + h*32);
            }
        }
        bf16x8 av[4][2], bv[2][2];
        #pragma unroll
        for (int i=0;i<4;i++)
            #pragma unroll
            for (int h=0;h<2;h++) av[i][h] = AS[(wy*4+i)*128 + h*64 + lane];
        #pragma unroll
        for (int j=0;j<2;j++)
            #pragma unroll
            for (int h=0;h<2;h++) bv[j][h] = BS[(wx*2+j)*128 + h*64 + lane];
        #pragma unroll
        for (int h=0;h<2;h++)
            #pragma unroll
            for (int i=0;i<4;i++)
                #pragma unroll
                for (int j=0;j<2;j++)
                    acc[i][j] = __builtin_amdgcn_mfma_f32_16x16x32_bf16(av[i][h], bv[j][h], acc[i][j], 0, 0, 0);
    }

    const int q = lane>>4, r = lane&15;
    if (MODE == 1) {
        #pragma unroll
        for (int j=0;j<2;j++) {
            int col = m0 + wx*32 + j*16 + r;
            if (col < M) {
                float bias = b1[col];
                #pragma unroll
                for (int i=0;i<4;i++)
                    #pragma unroll
                    for (int reg=0;reg<4;reg++) {
                        float v = fmaxf(acc[i][j][reg] + bias, 0.f);
                        ((bf16*)Cout)[(size_t)(n0 + wy*64 + i*16 + q*4 + reg)*ldc + col] = __float2bfloat16(v);
                    }
            }
        }
    } else {
        __syncthreads();                    // done with AS/BS
        #pragma unroll
        for (int j=0;j<2;j++) {
            int colL = wx*32 + j*16 + r;
            float bias = bint[m0 + colL];
            #pragma unroll
            for (int i=0;i<4;i++)
                #pragma unroll
                for (int reg=0;reg<4;reg++)
                    Gt[(wy*64 + i*16 + q*4 + reg)*68 + colL] = acc[i][j][reg] + bias;
        }
        __syncthreads();
        #pragma unroll
        for (int it=0; it<8; ++it) {
            int item = tid + it*256;        // 0..2047 : 128 rows x 16 units
            int rowL = item >> 4, u16 = item & 15;
            f32x4 gv = *(const f32x4*)&Gt[rowL*68 + u16*4];
            float ig = sigm(gv[0]);
            float fg = sigm(gv[1]);
            float gg = tanhf(gv[2]);
            float og = sigm(gv[3]);
            int n = n0 + rowL, u = (m0>>2) + u16;
            size_t cidx = (size_t)n*HIDD + u;
            float c2 = fg*c_r[cidx] + ig*gg;
            float hv = og*tanhf(c2);
            if (MODE == 2) {
                c_r[cidx] = c2;
                h_out[cidx] = hv;
                bf16 hb = __float2bfloat16(hv);
                rin_next[(size_t)n*RIN_LD + 462 + u] = hb;
                tin_[(size_t)n*TIN_LD + 2862 + u]    = hb;
            } else {
                h_out[cidx] = hv;
                out_htemp[((size_t)n*KO + kstep)*HIDD + u] = hv;
            }
        }
    }
}

// ================= glimpse core: LDS row-staged bilinear (fallback: global gather) ==========
__device__ __forceinline__ void glimpse_core(const float* __restrict__ im,
                                             float s, float tx, float ty,
                                             bf16* __restrict__ drow,
                                             float* __restrict__ rows) {
    const float GXS = 2.0f/49.0f;
    const float txp = tx + 1.0f, typ = ty + 1.0f;
    float pyA = fmaf(s, -1.f, typ)*63.5f;
    float pyB = fmaf(s,  1.f, typ)*63.5f;
    int ylo = (int)floorf(fminf(pyA, pyB));
    int yhi = (int)floorf(fmaxf(pyA, pyB)) + 1;
    ylo = min(max(ylo, 0), 127);
    yhi = min(max(yhi, 0), 127);
    int nrows = yhi - ylo + 1;

    if (nrows <= GROWS) {
        const float4* src = (const float4*)(im + ylo*IW);
        float4* d4 = (float4*)rows;
        int tot = nrows*(IW/4);
        for (int t = threadIdx.x; t < tot; t += 256) d4[t] = src[t];
        __syncthreads();
        for (int p2 = threadIdx.x; p2 < 1250; p2 += 256) {
            int i = p2 / 25, j = (p2 - i*25)*2;
            float gy  = fmaf((float)i, GXS, -1.0f);
            float py  = fmaf(s, gy, typ)*63.5f;
            float y0f = floorf(py); float fy = py - y0f; int y0 = (int)y0f;
            float wy0 = ((unsigned)y0     < 128u) ? (1.f - fy) : 0.f;
            float wy1 = ((unsigned)(y0+1) < 128u) ? fy         : 0.f;
            const float* r0 = rows + min(max(y0-ylo,   0), nrows-1)*IW;
            const float* r1 = rows + min(max(y0+1-ylo, 0), nrows-1)*IW;
            float gxa = fmaf((float)j, GXS, -1.0f);
            float pxa = fmaf(s, gxa, txp)*63.5f;
            float xa0f = floorf(pxa); float fa = pxa - xa0f; int xa0 = (int)xa0f;
            float wa0 = ((unsigned)xa0     < 128u) ? (1.f - fa) : 0.f;
            float wa1 = ((unsigned)(xa0+1) < 128u) ? fa         : 0.f;
            int xa0c = min(max(xa0,  0),127), xa1c = min(max(xa0+1,0),127);
            float gxb = fmaf((float)(j+1), GXS, -1.0f);
            float pxb = fmaf(s, gxb, txp)*63.5f;
            float xb0f = floorf(pxb); float fb = pxb - xb0f; int xb0 = (int)xb0f;
            float wb0 = ((unsigned)xb0     < 128u) ? (1.f - fb) : 0.f;
            float wb1 = ((unsigned)(xb0+1) < 128u) ? fb         : 0.f;
            int xb0c = min(max(xb0,  0),127), xb1c = min(max(xb0+1,0),127);
            float va = fmaf(wy1, fmaf(wa0, r1[xa0c], wa1*r1[xa1c]),
                       wy0 *     fmaf(wa0, r0[xa0c], wa1*r0[xa1c]));
            float vb = fmaf(wy1, fmaf(wb0, r1[xb0c], wb1*r1[xb1c]),
                       wy0 *     fmaf(wb0, r0[xb0c], wb1*r0[xb1c]));
            bf16 b0 = __float2bfloat16(va), b1 = __float2bfloat16(vb);
            unsigned short u0, u1;
            __builtin_memcpy(&u0, &b0, 2); __builtin_memcpy(&u1, &b1, 2);
            *(unsigned int*)(drow + i*GS + j) = (unsigned)u0 | ((unsigned)u1 << 16);
        }
    } else {
        for (int p2 = threadIdx.x; p2 < 1250; p2 += 256) {
            int i = p2 / 25, j = (p2 - i*25)*2;
            float gy  = fmaf((float)i, GXS, -1.0f);
            float py  = fmaf(s, gy, typ)*63.5f;
            float y0f = floorf(py); float fy = py - y0f; int y0 = (int)y0f;
            float wy0 = ((unsigned)y0     < 128u) ? (1.f - fy) : 0.f;
            float wy1 = ((unsigned)(y0+1) < 128u) ? fy         : 0.f;
            const float* r0 = im + min(max(y0,  0),127)*IW;
            const float* r1 = im + min(max(y0+1,0),127)*IW;
            float gxa = fmaf((float)j, GXS, -1.0f);
            float pxa = fmaf(s, gxa, txp)*63.5f;
            float xa0f = floorf(pxa); float fa = pxa - xa0f; int xa0 = (int)xa0f;
            float wa0 = ((unsigned)xa0     < 128u) ? (1.f - fa) : 0.f;
            float wa1 = ((unsigned)(xa0+1) < 128u) ? fa         : 0.f;
            int xa0c = min(max(xa0,  0),127), xa1c = min(max(xa0+1,0),127);
            float gxb = fmaf((float)(j+1), GXS, -1.0f);
            float pxb = fmaf(s, gxb, txp)*63.5f;
            float xb0f = floorf(pxb); float fb = pxb - xb0f; int xb0 = (int)xb0f;
            float wb0 = ((unsigned)xb0     < 128u) ? (1.f - fb) : 0.f;
            float wb1 = ((unsigned)(xb0+1) < 128u) ? fb         : 0.f;
            int xb0c = min(max(xb0,  0),127), xb1c = min(max(xb0+1,0),127);
            float va = fmaf(wy1, fmaf(wa0, r1[xa0c], wa1*r1[xa1c]),
                       wy0 *     fmaf(wa0, r0[xa0c], wa1*r0[xa1c]));
            float vb = fmaf(wy1, fmaf(wb0, r1[xb0c], wb1*r1[xb1c]),
                       wy0 *     fmaf(wb0, r0[xb0c], wb1*r0[xb1c]));
            bf16 b0 = __float2bfloat16(va), b1 = __float2bfloat16(vb);
            unsigned short u0, u1;
            __builtin_memcpy(&u0, &b0, 2); __builtin_memcpy(&u1, &b1, 2);
            *(unsigned int*)(drow + i*GS + j) = (unsigned)u0 | ((unsigned)u1 << 16);
        }
    }
}

__global__ __launch_bounds__(256) void glimpse_batch(const float* __restrict__ img,
                                                     const float* __restrict__ z,
                                                     bf16* __restrict__ dst, int ldd) {
    __shared__ float rows[GROWS*IW];
    int b = blockIdx.x;
    const float* im = img + (size_t)(b & (NN-1))*IH*IW;
    glimpse_core(im, z[b*3+0], z[b*3+1], z[b*3+2], dst + (size_t)b*ldd, rows);
}

// glimpse2 + zw linear + tin concat fill, fused (block per n)
__global__ __launch_bounds__(256) void glimpse2_zw(
    const float* __restrict__ img, const float* __restrict__ h_r,
    const float* __restrict__ z_where_last,
    const float* __restrict__ Wm_wh, const float* __restrict__ bm_wh,
    const float* __restrict__ zw_prev, const float* __restrict__ zwhat_prev,
    const float* __restrict__ z_what_last, const float* __restrict__ hidden_last,
    float* __restrict__ zw_cur, float* __restrict__ out_zwhere,
    bf16* __restrict__ tin, bf16* __restrict__ rin_next, int k)
{
    __shared__ float rows[GROWS*IW];
    __shared__ float hsv[HIDD];
    __shared__ float zws[3];
    int n = blockIdx.x, tid = threadIdx.x;
    hsv[tid] = h_r[(size_t)n*HIDD + tid];
    __syncthreads();
    int wv = tid>>6, lane = tid&63;
    if (wv < 3) {
        const float* wt = Wm_wh + wv*259;
        float sa = 0.f;
        for (int i = lane; i < 256; i += 64) sa = fmaf(hsv[i], wt[3+i], sa);
        #pragma unroll
        for (int off=32; off; off>>=1) sa += __shfl_down(sa, off);
        if (lane == 0) {
            const float* zwl = z_where_last + ((size_t)n*KO + k)*3;
            float acc = bm_wh[wv] + sa;
            for (int i=0;i<3;i++) acc = fmaf(zwl[i], wt[i], acc);
            zws[wv] = acc;
            zw_cur[n*3+wv] = acc;
            out_zwhere[((size_t)n*KO + k)*3 + wv] = acc;
            bf16 ab = __float2bfloat16(acc);
            rin_next[(size_t)n*RIN_LD + 103 + wv] = ab;
            tin[(size_t)n*TIN_LD + 2500 + wv]     = ab;
        }
    }
    __syncthreads();
    float s = zws[0], tx = zws[1], ty = zws[2];
    bf16* trow = tin + (size_t)n*TIN_LD;
    glimpse_core(img + (size_t)n*IH*IW, s, tx, ty, trow, rows);
    for (int c = 3 + tid; c < 362; c += 256) {
        float v;
        if      (c <   6) v = zw_prev[n*3 + c-3];
        else if (c <  56) v = z_what_last[((size_t)n*KO + k)*50 + c-6];
        else if (c < 106) v = zwhat_prev[n*50 + c-56];
        else              v = hidden_last[((size_t)n*KO + k)*HIDD + c-106];
        trow[2500 + c] = __float2bfloat16(v);
    }
}

// ================= small / preamble kernels =================
__global__ void zero_f32(float* __restrict__ p, int n) {
    int i = blockIdx.x*blockDim.x + threadIdx.x;
    if (i < n) p[i] = 0.f;
}

__global__ void repack_w(const float* __restrict__ s1, int K1,
                         const float* __restrict__ s2, int K2,
                         bf16* __restrict__ dst, int ldd, int M) {
    int gid = blockIdx.x*blockDim.x + threadIdx.x;
    if (gid >= M*ldd) return;
    int m = gid / ldd, c = gid - m*ldd;
    float v = 0.f;
    if (c < K1)           v = s1[(size_t)m*K1 + c];
    else if (c < K1+K2)   v = s2[(size_t)m*K2 + (c-K1)];
    dst[gid] = __float2bfloat16(v);
}

// gate-interleaved repack: dst row 4u+g  <-  src row g*256+u
__global__ void repack_w_gates(const float* __restrict__ s1, int K1,
                               const float* __restrict__ s2, int K2,
                               bf16* __restrict__ dst, int ldd) {
    int gid = blockIdx.x*blockDim.x + threadIdx.x;
    if (gid >= 1024*ldd) return;
    int mp = gid / ldd, c = gid - mp*ldd;
    int u = mp >> 2, g = mp & 3;
    int m = g*256 + u;
    float v = 0.f;
    if (c < K1)           v = s1[(size_t)m*K1 + c];
    else if (c < K1+K2)   v = s2[(size_t)m*K2 + (c-K1)];
    dst[gid] = __float2bfloat16(v);
}

__global__ void repack_bias_gates(const float* __restrict__ b1, const float* __restrict__ b2,
                                  float* __restrict__ dst) {
    int mp = blockIdx.x*blockDim.x + threadIdx.x;
    if (mp >= 1024) return;
    int u = mp >> 2, g = mp & 3;
    dst[mp] = b1[g*256+u] + b2[g*256+u];
}

__global__ __launch_bounds__(256) void zwb_all_v2(const float* __restrict__ hidden_last,
                                                  const float* __restrict__ z_where_last,
                                                  const float* __restrict__ Wl, const float* __restrict__ bl,
                                                  float* __restrict__ zwb_all) {
    __shared__ float wls[768];
    for (int i = threadIdx.x; i < 768; i += 256) wls[i] = Wl[i];
    __syncthreads();
    int wv = threadIdx.x>>6, lane = threadIdx.x&63;
    int row = blockIdx.x*4 + wv;
    int s = row >> 11, n = row & (NN-1);
    const float* hl = hidden_last + ((size_t)n*KO + s)*HIDD;
    float4 h4 = *(const float4*)(hl + lane*4);
    float s0=0.f, s1=0.f, s2=0.f;
    #pragma unroll
    for (int r4=0;r4<4;r4++) {
        float hv = ((const float*)&h4)[r4];
        int i = lane*4 + r4;
        s0 = fmaf(hv, wls[i],     s0);
        s1 = fmaf(hv, wls[256+i], s1);
        s2 = fmaf(hv, wls[512+i], s2);
    }
    #pragma unroll
    for (int off=32; off; off>>=1) {
        s0 += __shfl_down(s0,off); s1 += __shfl_down(s1,off); s2 += __shfl_down(s2,off);
    }
    if (lane == 0) {
        const float* zwl = z_where_last + ((size_t)n*KO + s)*3;
        zwb_all[row*3+0] = fmaxf(s0+bl[0],0.f) + zwl[0];
        zwb_all[row*3+1] = fmaxf(s1+bl[1],0.f) + zwl[1];
        zwb_all[row*3+2] = fmaxf(s2+bl[2],0.f) + zwl[2];
    }
}

__global__ void fill_rin_static(bf16* __restrict__ rin,
                                const float* __restrict__ z_where_last,
                                const float* __restrict__ z_what_last,
                                const float* __restrict__ hidden_last,
                                int base, int CH) {
    int gid = blockIdx.x*blockDim.x + threadIdx.x;
    if (gid >= CH*NN*309) return;
    int c = gid % 309; int rn = gid/309; int n = rn & (NN-1); int sl = rn >> 11;
    int k = base + sl;
    float v; int col;
    if (c < 3)       { col = 100 + c;      v = z_where_last[((size_t)n*KO + k)*3 + c]; }
    else if (c < 53) { col = 106 + (c-3);  v = z_what_last[((size_t)n*KO + k)*50 + (c-3)]; }
    else             { col = 206 + (c-53); v = hidden_last[((size_t)n*KO + k)*HIDD + (c-53)]; }
    rin[(size_t)rn*RIN_LD + col] = __float2bfloat16(v);
}

__global__ void zero_rin_carry(bf16* __restrict__ rin0) {
    int gid = blockIdx.x*blockDim.x + threadIdx.x;
    if (gid >= NN*309) return;
    int c = gid % 309, n = gid/309;
    int col = (c < 3) ? 103+c : ((c < 53) ? 156+(c-3) : 462+(c-53));
    rin0[(size_t)n*RIN_LD + col] = __float2bfloat16(0.f);
}

// ================= tem tail: zwhat + pres (block per n) =================
__global__ __launch_bounds__(256) void tem_tail(
    const float* __restrict__ h_r, const float* __restrict__ h_t,
    const float* __restrict__ z_what_last,
    const float* __restrict__ Wm_wt, const float* __restrict__ bm_wt,
    const float* __restrict__ Wm_pr, const float* __restrict__ bm_pr,
    const float* __restrict__ Ws_pr, const float* __restrict__ bs_pr,
    const float* __restrict__ zw_cur, const float* __restrict__ z_pres_last,
    float* __restrict__ zwhat_cur, float* __restrict__ out_zwhat,
    float* __restrict__ out_zpres, bf16* __restrict__ rin_next, int k)
{
    __shared__ float L[615];
    int n = blockIdx.x, j = threadIdx.x;
    L[309+j] = h_t[(size_t)n*HIDD + j];
    L[53+j]  = h_r[(size_t)n*HIDD + j];
    if (j < 50)      L[j] = z_what_last[((size_t)n*KO + k)*50 + j];
    else if (j < 53) L[j] = zw_cur[n*3 + (j-50)];
    __syncthreads();
    if (j < 200) {
        int m = j >> 2, part = j & 3;
        const float* wt = Wm_wt + m*562;
        float sa = 0.f;
        for (int i = part; i < 562; i += 4) {
            float v = (i < 50) ? L[i] : L[i+3];
            sa = fmaf(v, wt[i], sa);
        }
        sa += __shfl_down(sa, 2);
        sa += __shfl_down(sa, 1);
        if (part == 0) {
            float acc = sa + bm_wt[m];
            zwhat_cur[n*50+m] = acc;
            out_zwhat[((size_t)n*KO + k)*50 + m] = acc;
            rin_next[(size_t)n*RIN_LD + 156 + m] = __float2bfloat16(acc);
            L[565+m] = acc;
        }
    }
    __syncthreads();
    if (j < 64) {
        float s1 = 0.f, s2 = 0.f;
        for (int i = j; i < 565; i += 64) {
            float v = (i < 50) ? L[565+i] : L[i];
            s1 = fmaf(v, Wm_pr[i], s1);
            s2 = fmaf(v, Ws_pr[i], s2);
        }
        #pragma unroll
        for (int off = 32; off; off >>= 1) { s1 += __shfl_down(s1,off); s2 += __shfl_down(s2,off); }
        if (j == 0) {
            float p = sigm(s1 + bm_pr[0]) * sigm(s2 + bs_pr[0]);
            out_zpres[(size_t)n*KO + k] = p * z_pres_last[(size_t)n*KO + k];
        }
    }
}

extern "C" void kernel_launch(void* const* d_in, const int* in_sizes, int n_in,
                              void* d_out, int out_size, void* d_ws, size_t ws_size,
                              hipStream_t stream) {
    (void)in_sizes; (void)n_in; (void)out_size;
    const float* img          = (const float*)d_in[0];
    const float* z_what_last  = (const float*)d_in[1];
    const float* z_where_last = (const float*)d_in[2];
    const float* z_pres_last  = (const float*)d_in[3];
    const float* hidden_last  = (const float*)d_in[4];
    const float* W_loca = (const float*)d_in[5];
    const float* b_loca = (const float*)d_in[6];
    const float* Wg     = (const float*)d_in[7];
    const float* bg     = (const float*)d_in[8];
    const float* Wih_rel = (const float*)d_in[9];
    const float* Whh_rel = (const float*)d_in[10];
    const float* bih_rel = (const float*)d_in[11];
    const float* bhh_rel = (const float*)d_in[12];
    const float* Wih_tem = (const float*)d_in[13];
    const float* Whh_tem = (const float*)d_in[14];
    const float* bih_tem = (const float*)d_in[15];
    const float* bhh_tem = (const float*)d_in[16];
    const float* Wm_wh = (const float*)d_in[17];
    const float* bm_wh = (const float*)d_in[18];
    const float* Wm_wt = (const float*)d_in[21];
    const float* bm_wt = (const float*)d_in[22];
    const float* Wm_pr = (const float*)d_in[25];
    const float* bm_pr = (const float*)d_in[26];
    const float* Ws_pr = (const float*)d_in[27];
    const float* bs_pr = (const float*)d_in[28];

    char* base_p = (char*)d_ws;
    size_t off = 0;
    auto carve = [&](size_t bytes) -> char* {
        char* r = base_p + off;
        off += (bytes + 255) & ~(size_t)255;
        return r;
    };
    bf16*  tin      = (bf16*) carve((size_t)NN*TIN_LD*2);
    bf16*  W_tem    = (bf16*) carve((size_t)1024*TIN_LD*2);
    bf16*  W_rel    = (bf16*) carve((size_t)1024*RIN_LD*2);
    bf16*  Wg_bf    = (bf16*) carve((size_t)100*G1_LD*2);
    float* bint_rel = (float*)carve(1024*4);
    float* bint_tem = (float*)carve(1024*4);
    float* zwb_all  = (float*)carve((size_t)KO*NN*3*4);
    float* h_r      = (float*)carve((size_t)NN*HIDD*4);
    float* h_t      = (float*)carve((size_t)NN*HIDD*4);
    float* c_r      = (float*)carve((size_t)NN*HIDD*4);
    float* zw1      = (float*)carve((size_t)NN*3*4);
    float* zwhat1   = (float*)carve((size_t)NN*50*4);
    float* zw0      = (float*)carve((size_t)NN*3*4);
    float* zwhat0   = (float*)carve((size_t)NN*50*4);
    size_t fixed_bytes = off;

    int CH = 1;
    for (int cand : {8, 4, 2}) {
        size_t need = fixed_bytes
                    + (((size_t)cand*NN*G1_LD*2 + 255) & ~(size_t)255)
                    + (((size_t)cand*NN*RIN_LD*2 + 255) & ~(size_t)255);
        if (need <= ws_size) { CH = cand; break; }
    }
    bf16* g1 = nullptr; int g1ld;
    bf16* rin;
    if (CH > 1) {
        g1   = (bf16*)carve((size_t)CH*NN*G1_LD*2);
        rin  = (bf16*)carve((size_t)CH*NN*RIN_LD*2);
        g1ld = G1_LD;
    } else {
        rin  = (bf16*)carve((size_t)NN*RIN_LD*2);
        g1   = tin;
        g1ld = TIN_LD;
    }

    float* out        = (float*)d_out;
    float* out_zwhat  = out;
    float* out_zwhere = out + (size_t)NN*KO*50;
    float* out_zpres  = out_zwhere + (size_t)NN*KO*3;
    float* out_htemp  = out_zpres + (size_t)NN*KO;

    // ---- preamble ----
    {
        int nz = NN*(HIDD + 3 + 50);
        zero_f32<<<(nz+255)/256, 256, 0, stream>>>(c_r, nz);
    }
    zero_rin_carry<<<(NN*309+255)/256, 256, 0, stream>>>(rin);
    repack_w_gates<<<((1024*RIN_LD)+255)/256, 256, 0, stream>>>(Wih_rel, 462, Whh_rel, 256, W_rel, RIN_LD);
    repack_w_gates<<<((1024*TIN_LD)+255)/256, 256, 0, stream>>>(Wih_tem, 2862, Whh_tem, 256, W_tem, TIN_LD);
    repack_w<<<((100*G1_LD)+255)/256, 256, 0, stream>>>(Wg, 2500, nullptr, 0, Wg_bf, G1_LD, 100);
    repack_bias_gates<<<4, 256, 0, stream>>>(bih_rel, bhh_rel, bint_rel);
    repack_bias_gates<<<4, 256, 0, stream>>>(bih_tem, bhh_tem, bint_tem);
    zwb_all_v2<<<KO*NN/4, 256, 0, stream>>>(hidden_last, z_where_last, W_loca, b_loca, zwb_all);

    for (int cbase = 0; cbase < KO; cbase += CH) {
        fill_rin_static<<<(CH*NN*309+255)/256, 256, 0, stream>>>(rin, z_where_last, z_what_last, hidden_last, cbase, CH);
        glimpse_batch<<<CH*NN, 256, 0, stream>>>(img, zwb_all + (size_t)cbase*NN*3, g1, g1ld);
        mfma_gemm<1><<<dim3(2, CH*16), 256, 0, stream>>>(g1, g1ld, G1_LD, Wg_bf, G1_LD, 100,
            bg, nullptr, rin, RIN_LD, nullptr, nullptr, nullptr, nullptr, nullptr, 0);

        for (int s = 0; s < CH; ++s) {
            int k = cbase + s;
            bf16* rin_k  = rin + (size_t)s*NN*RIN_LD;
            bf16* rin_nx = rin + (size_t)((s+1)%CH)*NN*RIN_LD;
            float* zw_cur     = (k & 1) ? zw1 : zw0;
            float* zw_prev    = (k & 1) ? zw0 : zw1;
            float* zwhat_cur  = (k & 1) ? zwhat1 : zwhat0;
            float* zwhat_prev = (k & 1) ? zwhat0 : zwhat1;

            mfma_gemm<2><<<dim3(16, 16), 256, 0, stream>>>(rin_k, RIN_LD, RIN_LD, W_rel, RIN_LD, 1024,
                nullptr, bint_rel, nullptr, 0, c_r, h_r, rin_nx, tin, nullptr, k);
            glimpse2_zw<<<NN, 256, 0, stream>>>(img, h_r, z_where_last, Wm_wh, bm_wh,
                zw_prev, zwhat_prev, z_what_last, hidden_last, zw_cur, out_zwhere, tin, rin_nx, k);
            mfma_gemm<3><<<dim3(16, 16), 256, 0, stream>>>(tin, TIN_LD, TIN_LD, W_tem, TIN_LD, 1024,
                nullptr, bint_tem, nullptr, 0, c_r, h_t, nullptr, nullptr, out_htemp, k);
            tem_tail<<<NN, 256, 0, stream>>>(h_r, h_t, z_what_last, Wm_wt, bm_wt,
                Wm_pr, bm_pr, Ws_pr, bs_pr, zw_cur, z_pres_last,
                zwhat_cur, out_zwhat, out_zpres, rin_nx, k);
        }
    }
}

// Round 8
// 1344.086 us; speedup vs baseline: 1.0913x; 1.0913x over previous
//
#include <hip/hip_runtime.h>
#include <hip/hip_bf16.h>
#include <math.h>

typedef __attribute__((ext_vector_type(8))) short bf16x8;
typedef __attribute__((ext_vector_type(4))) float f32x4;
using bf16 = __hip_bfloat16;

constexpr int NN   = 2048;
constexpr int KO   = 8;
constexpr int IH   = 128, IW = 128;
constexpr int GS   = 50;
constexpr int HIDD = 256;
// rin: [enc 0..100 | zwl 100..103 | pzw 103..106 | zwhatl 106..156 | pzwhat 156..206 | hl 206..462 | h_r 462..718 | pad..768]
constexpr int RIN_LD = 768;
// tin: [g2 0..2500 | zw 2500..2503 | pzw 2503..2506 | zwhatl 2506..2556 | pzwhat 2556..2606 | hl 2606..2862 | h_r2 2862..3118 | pad..3136]
constexpr int TIN_LD = 3136;
constexpr int G1_LD  = 2560;
constexpr int GROWS  = 64;        // LDS-staged image rows for glimpse1 (32 KB)

__device__ __forceinline__ float sigm(float x) { return 1.f/(1.f+expf(-x)); }

// ================= MFMA GEMM v3 + XCD swizzle: 64x64 tile, BK=64, 2 blocks/CU ==================
// C[N][M] = A[N][Kd] @ W[M][Kd]^T. 4 waves, wave tile 32x32 (2x2 16x16x32 frags).
// 1D grid, multiple of 8. Decode: xcd=b&7, t=b>>3, xb=t%nxb, yb=xcd+8*(t/nxb).
// -> each XCD processes row-panels {xcd, xcd+8, ...} across all col-blocks: A panels stay in its L2.
template<int OUT_BF16, int RELU>
__global__ __launch_bounds__(256, 2) void mfma_gemm(
    const bf16* __restrict__ A, int lda, int Kd,
    const bf16* __restrict__ Wt, int ldw, int M,
    const float* __restrict__ b1, const float* __restrict__ b2,
    void* __restrict__ Cout, int ldc, int nxb)
{
    __shared__ bf16x8 As16[512];   // 4 rowgroups x 2 khalves x 64 lanes (8 KB)
    __shared__ bf16x8 Bs16[512];
    const int b    = blockIdx.x;
    const int xcd  = b & 7;
    const int t    = b >> 3;
    const int n0   = (xcd + 8*(t / nxb))*64;
    const int m0   = (t % nxb)*64;
    const int tid  = threadIdx.x;
    const int wave = tid>>6, lane = tid&63;
    const int wy   = wave>>1, wx = wave&1;

    const int row = tid>>2, part = tid&3;
    const bf16* Ap = A + (size_t)(n0+row)*lda + part*8;
    const int   wm = m0 + row;
    const bool  wok = wm < M;
    const bf16* Wp = Wt + (size_t)(wok ? wm : 0)*ldw + part*8;
    const int dst0 = ((row>>4)*2+0)*64 + part*16 + (row&15);
    const int dst1 = dst0 + 64;

    f32x4 acc[2][2] = {};
    const bf16x8 z8 = {};
    bf16x8 pa0 = *(const bf16x8*)Ap;
    bf16x8 pa1 = *(const bf16x8*)(Ap + 32);
    bf16x8 pw0 = *(const bf16x8*)Wp;
    bf16x8 pw1 = *(const bf16x8*)(Wp + 32);

    for (int k0 = 0; k0 < Kd; k0 += 64) {
        __syncthreads();
        As16[dst0] = pa0;
        As16[dst1] = pa1;
        Bs16[dst0] = wok ? pw0 : z8;
        Bs16[dst1] = wok ? pw1 : z8;
        __syncthreads();
        if (k0 + 64 < Kd) {            // prefetch next K-tile during MFMA phase
            pa0 = *(const bf16x8*)(Ap + k0 + 64);
            pa1 = *(const bf16x8*)(Ap + k0 + 96);
            pw0 = *(const bf16x8*)(Wp + k0 + 64);
            pw1 = *(const bf16x8*)(Wp + k0 + 96);
        }
        bf16x8 av[2][2], bv[2][2];
        #pragma unroll
        for (int i=0;i<2;i++)
            #pragma unroll
            for (int h=0;h<2;h++) av[i][h] = As16[((wy*2+i)*2+h)*64 + lane];
        #pragma unroll
        for (int j=0;j<2;j++)
            #pragma unroll
            for (int h=0;h<2;h++) bv[j][h] = Bs16[((wx*2+j)*2+h)*64 + lane];
        #pragma unroll
        for (int h=0;h<2;h++)
            #pragma unroll
            for (int i=0;i<2;i++)
                #pragma unroll
                for (int j=0;j<2;j++)
                    acc[i][j] = __builtin_amdgcn_mfma_f32_16x16x32_bf16(av[i][h], bv[j][h], acc[i][j], 0, 0, 0);
    }

    const int q = lane>>4, r = lane&15;
    #pragma unroll
    for (int j=0;j<2;j++) {
        int col = m0 + wx*32 + j*16 + r;
        if (col < M) {
            float bias = 0.f;
            if (b1) bias += b1[col];
            if (b2) bias += b2[col];
            #pragma unroll
            for (int i=0;i<2;i++) {
                #pragma unroll
                for (int reg=0;reg<4;reg++) {
                    float v = acc[i][j][reg] + bias;
                    if (RELU) v = fmaxf(v, 0.f);
                    size_t idx = (size_t)(n0 + wy*32 + i*16 + q*4 + reg)*ldc + col;
                    if (OUT_BF16) ((bf16*)Cout)[idx] = __float2bfloat16(v);
                    else          ((float*)Cout)[idx] = v;
                }
            }
        }
    }
}

// ================= glimpse point math (global-gather path) =================
__device__ __forceinline__ void glimpse_points_global(const float* __restrict__ im,
                                                      float s, float tx, float ty,
                                                      bf16* __restrict__ drow) {
    const float GXS = 2.0f/49.0f;
    const float txp = tx + 1.0f, typ = ty + 1.0f;
    for (int p2 = threadIdx.x; p2 < 1250; p2 += 256) {
        int i = p2 / 25, j = (p2 - i*25)*2;
        float gy  = fmaf((float)i, GXS, -1.0f);
        float py  = fmaf(s, gy, typ)*63.5f;
        float y0f = floorf(py); float fy = py - y0f; int y0 = (int)y0f;
        float wy0 = ((unsigned)y0     < 128u) ? (1.f - fy) : 0.f;
        float wy1 = ((unsigned)(y0+1) < 128u) ? fy         : 0.f;
        const float* r0 = im + min(max(y0,  0),127)*IW;
        const float* r1 = im + min(max(y0+1,0),127)*IW;
        float gxa = fmaf((float)j, GXS, -1.0f);
        float pxa = fmaf(s, gxa, txp)*63.5f;
        float xa0f = floorf(pxa); float fa = pxa - xa0f; int xa0 = (int)xa0f;
        float wa0 = ((unsigned)xa0     < 128u) ? (1.f - fa) : 0.f;
        float wa1 = ((unsigned)(xa0+1) < 128u) ? fa         : 0.f;
        int xa0c = min(max(xa0,  0),127), xa1c = min(max(xa0+1,0),127);
        float gxb = fmaf((float)(j+1), GXS, -1.0f);
        float pxb = fmaf(s, gxb, txp)*63.5f;
        float xb0f = floorf(pxb); float fb = pxb - xb0f; int xb0 = (int)xb0f;
        float wb0 = ((unsigned)xb0     < 128u) ? (1.f - fb) : 0.f;
        float wb1 = ((unsigned)(xb0+1) < 128u) ? fb         : 0.f;
        int xb0c = min(max(xb0,  0),127), xb1c = min(max(xb0+1,0),127);

        float va = fmaf(wy1, fmaf(wa0, r1[xa0c], wa1*r1[xa1c]),
                   wy0 *     fmaf(wa0, r0[xa0c], wa1*r0[xa1c]));
        float vb = fmaf(wy1, fmaf(wb0, r1[xb0c], wb1*r1[xb1c]),
                   wy0 *     fmaf(wb0, r0[xb0c], wb1*r0[xb1c]));

        bf16 b0 = __float2bfloat16(va), b1 = __float2bfloat16(vb);
        unsigned short u0, u1;
        __builtin_memcpy(&u0, &b0, 2); __builtin_memcpy(&u1, &b1, 2);
        *(unsigned int*)(drow + i*GS + j) = (unsigned)u0 | ((unsigned)u1 << 16);
    }
}

// ================= glimpse1: LDS row-staged (proven -17us), fallback global ==========
__global__ __launch_bounds__(256) void glimpse_batch(const float* __restrict__ img,
                                                     const float* __restrict__ z,
                                                     bf16* __restrict__ dst, int ldd) {
    __shared__ float rows[GROWS*IW];
    int b = blockIdx.x;
    const float* im = img + (size_t)(b & (NN-1))*IH*IW;
    float s  = z[b*3+0];
    float tx = z[b*3+1];
    float ty = z[b*3+2];
    bf16* drow = dst + (size_t)b*ldd;

    const float GXS = 2.0f/49.0f;
    const float txp = tx + 1.0f, typ = ty + 1.0f;
    float pyA = fmaf(s, -1.f, typ)*63.5f;
    float pyB = fmaf(s,  1.f, typ)*63.5f;
    int ylo = (int)floorf(fminf(pyA, pyB));
    int yhi = (int)floorf(fmaxf(pyA, pyB)) + 1;
    ylo = min(max(ylo, 0), 127);
    yhi = min(max(yhi, 0), 127);
    int nrows = yhi - ylo + 1;

    if (nrows <= GROWS) {
        const float4* src = (const float4*)(im + ylo*IW);
        float4* d4 = (float4*)rows;
        int tot = nrows*(IW/4);
        for (int t = threadIdx.x; t < tot; t += 256) d4[t] = src[t];
        __syncthreads();
        for (int p2 = threadIdx.x; p2 < 1250; p2 += 256) {
            int i = p2 / 25, j = (p2 - i*25)*2;
            float gy  = fmaf((float)i, GXS, -1.0f);
            float py  = fmaf(s, gy, typ)*63.5f;
            float y0f = floorf(py); float fy = py - y0f; int y0 = (int)y0f;
            float wy0 = ((unsigned)y0     < 128u) ? (1.f - fy) : 0.f;
            float wy1 = ((unsigned)(y0+1) < 128u) ? fy         : 0.f;
            const float* r0 = rows + min(max(y0-ylo,   0), nrows-1)*IW;
            const float* r1 = rows + min(max(y0+1-ylo, 0), nrows-1)*IW;
            float gxa = fmaf((float)j, GXS, -1.0f);
            float pxa = fmaf(s, gxa, txp)*63.5f;
            float xa0f = floorf(pxa); float fa = pxa - xa0f; int xa0 = (int)xa0f;
            float wa0 = ((unsigned)xa0     < 128u) ? (1.f - fa) : 0.f;
            float wa1 = ((unsigned)(xa0+1) < 128u) ? fa         : 0.f;
            int xa0c = min(max(xa0,  0),127), xa1c = min(max(xa0+1,0),127);
            float gxb = fmaf((float)(j+1), GXS, -1.0f);
            float pxb = fmaf(s, gxb, txp)*63.5f;
            float xb0f = floorf(pxb); float fb = pxb - xb0f; int xb0 = (int)xb0f;
            float wb0 = ((unsigned)xb0     < 128u) ? (1.f - fb) : 0.f;
            float wb1 = ((unsigned)(xb0+1) < 128u) ? fb         : 0.f;
            int xb0c = min(max(xb0,  0),127), xb1c = min(max(xb0+1,0),127);
            float va = fmaf(wy1, fmaf(wa0, r1[xa0c], wa1*r1[xa1c]),
                       wy0 *     fmaf(wa0, r0[xa0c], wa1*r0[xa1c]));
            float vb = fmaf(wy1, fmaf(wb0, r1[xb0c], wb1*r1[xb1c]),
                       wy0 *     fmaf(wb0, r0[xb0c], wb1*r0[xb1c]));
            bf16 b0 = __float2bfloat16(va), b1 = __float2bfloat16(vb);
            unsigned short u0, u1;
            __builtin_memcpy(&u0, &b0, 2); __builtin_memcpy(&u1, &b1, 2);
            *(unsigned int*)(drow + i*GS + j) = (unsigned)u0 | ((unsigned)u1 << 16);
        }
    } else {
        glimpse_points_global(im, s, tx, ty, drow);
    }
}

// ================= glimpse2 fused with tin concat fill (r4 version: no LDS, L1-bound) =======
__global__ __launch_bounds__(256) void glimpse2_fused(const float* __restrict__ img,
                                                      const float* __restrict__ zw_cur,
                                                      const float* __restrict__ zw_prev,
                                                      const float* __restrict__ zwhat_prev,
                                                      const float* __restrict__ z_what_last,
                                                      const float* __restrict__ hidden_last,
                                                      bf16* __restrict__ tin, int k) {
    int n = blockIdx.x;
    const float* im = img + (size_t)n*IH*IW;
    float s  = zw_cur[n*3+0];
    float tx = zw_cur[n*3+1];
    float ty = zw_cur[n*3+2];
    bf16* trow = tin + (size_t)n*TIN_LD;
    glimpse_points_global(im, s, tx, ty, trow);
    for (int c = threadIdx.x; c < 362; c += 256) {
        float v;
        if      (c <   3) v = (c==0) ? s : ((c==1) ? tx : ty);
        else if (c <   6) v = zw_prev[n*3 + c-3];
        else if (c <  56) v = z_what_last[((size_t)n*KO + k)*50 + c-6];
        else if (c < 106) v = zwhat_prev[n*50 + c-56];
        else              v = hidden_last[((size_t)n*KO + k)*HIDD + c-106];
        trow[2500 + c] = __float2bfloat16(v);
    }
}

// ================= small / preamble kernels =================
__global__ void zero_f32(float* __restrict__ p, int n) {
    int i = blockIdx.x*blockDim.x + threadIdx.x;
    if (i < n) p[i] = 0.f;
}

__global__ void repack_w(const float* __restrict__ s1, int K1,
                         const float* __restrict__ s2, int K2,
                         bf16* __restrict__ dst, int ldd, int M) {
    int gid = blockIdx.x*blockDim.x + threadIdx.x;
    if (gid >= M*ldd) return;
    int m = gid / ldd, c = gid - m*ldd;
    float v = 0.f;
    if (c < K1)           v = s1[(size_t)m*K1 + c];
    else if (c < K1+K2)   v = s2[(size_t)m*K2 + (c-K1)];
    dst[gid] = __float2bfloat16(v);
}

__global__ __launch_bounds__(256) void zwb_all_v2(const float* __restrict__ hidden_last,
                                                  const float* __restrict__ z_where_last,
                                                  const float* __restrict__ Wl, const float* __restrict__ bl,
                                                  float* __restrict__ zwb_all) {
    __shared__ float wls[768];
    for (int i = threadIdx.x; i < 768; i += 256) wls[i] = Wl[i];
    __syncthreads();
    int wv = threadIdx.x>>6, lane = threadIdx.x&63;
    int row = blockIdx.x*4 + wv;
    int s = row >> 11, n = row & (NN-1);
    const float* hl = hidden_last + ((size_t)n*KO + s)*HIDD;
    float4 h4 = *(const float4*)(hl + lane*4);
    float s0=0.f, s1=0.f, s2=0.f;
    #pragma unroll
    for (int r4=0;r4<4;r4++) {
        float hv = ((const float*)&h4)[r4];
        int i = lane*4 + r4;
        s0 = fmaf(hv, wls[i],     s0);
        s1 = fmaf(hv, wls[256+i], s1);
        s2 = fmaf(hv, wls[512+i], s2);
    }
    #pragma unroll
    for (int off=32; off; off>>=1) {
        s0 += __shfl_down(s0,off); s1 += __shfl_down(s1,off); s2 += __shfl_down(s2,off);
    }
    if (lane == 0) {
        const float* zwl = z_where_last + ((size_t)n*KO + s)*3;
        zwb_all[row*3+0] = fmaxf(s0+bl[0],0.f) + zwl[0];
        zwb_all[row*3+1] = fmaxf(s1+bl[1],0.f) + zwl[1];
        zwb_all[row*3+2] = fmaxf(s2+bl[2],0.f) + zwl[2];
    }
}

__global__ void fill_rin_static(bf16* __restrict__ rin,
                                const float* __restrict__ z_where_last,
                                const float* __restrict__ z_what_last,
                                const float* __restrict__ hidden_last,
                                int base, int CH) {
    int gid = blockIdx.x*blockDim.x + threadIdx.x;
    if (gid >= CH*NN*309) return;
    int c = gid % 309; int rn = gid/309; int n = rn & (NN-1); int sl = rn >> 11;
    int k = base + sl;
    float v; int col;
    if (c < 3)       { col = 100 + c;      v = z_where_last[((size_t)n*KO + k)*3 + c]; }
    else if (c < 53) { col = 106 + (c-3);  v = z_what_last[((size_t)n*KO + k)*50 + (c-3)]; }
    else             { col = 206 + (c-53); v = hidden_last[((size_t)n*KO + k)*HIDD + (c-53)]; }
    rin[(size_t)rn*RIN_LD + col] = __float2bfloat16(v);
}

__global__ void zero_rin_carry(bf16* __restrict__ rin0) {
    int gid = blockIdx.x*blockDim.x + threadIdx.x;
    if (gid >= NN*309) return;
    int c = gid % 309, n = gid/309;
    int col = (c < 3) ? 103+c : ((c < 53) ? 156+(c-3) : 462+(c-53));
    rin0[(size_t)n*RIN_LD + col] = __float2bfloat16(0.f);
}

// ================= fused step kernels (block per n) — r4 proven versions =================
__global__ __launch_bounds__(256) void rel_fused(
    const float* __restrict__ gates, float* __restrict__ h_r, float* __restrict__ c_r,
    const float* __restrict__ z_where_last,
    const float* __restrict__ Wm_wh, const float* __restrict__ bm_wh,
    float* __restrict__ zw_cur, float* __restrict__ out_zwhere,
    bf16* __restrict__ rin_next, bf16* __restrict__ tin, int k)
{
    __shared__ float hs[256];
    int n = blockIdx.x, j = threadIdx.x;
    const float* g = gates + (size_t)n*1024;
    float ig = sigm(g[j]);
    float fg = sigm(g[256+j]);
    float gg = tanhf(g[512+j]);
    float og = sigm(g[768+j]);
    int cidx = n*256 + j;
    float c2 = fg*c_r[cidx] + ig*gg;
    float hv = og*tanhf(c2);
    c_r[cidx] = c2;
    h_r[cidx] = hv;
    hs[j] = hv;
    bf16 hb = __float2bfloat16(hv);
    rin_next[(size_t)n*RIN_LD + 462 + j] = hb;
    tin[(size_t)n*TIN_LD + 2862 + j]     = hb;
    __syncthreads();
    int w = j >> 6, lane = j & 63;
    if (w < 3) {
        const float* wt = Wm_wh + w*259;
        float s = 0.f;
        for (int i = lane; i < 256; i += 64) s = fmaf(hs[i], wt[3+i], s);
        #pragma unroll
        for (int off = 32; off; off >>= 1) s += __shfl_down(s, off);
        if (lane == 0) {
            const float* zwl = z_where_last + ((size_t)n*KO + k)*3;
            float acc = bm_wh[w] + s;
            for (int i = 0; i < 3; i++) acc = fmaf(zwl[i], wt[i], acc);
            zw_cur[n*3+w] = acc;
            out_zwhere[((size_t)n*KO + k)*3 + w] = acc;
            rin_next[(size_t)n*RIN_LD + 103 + w] = __float2bfloat16(acc);
        }
    }
}

// tem LSTM elementwise + zwhat + pres. LDS: [zwhatl 0..50 | zw 50..53 | hr 53..309 | ht 309..565 | zwhat 565..615]
__global__ __launch_bounds__(256) void tem_fused(
    const float* __restrict__ gates, const float* __restrict__ c_r, const float* __restrict__ h_r,
    const float* __restrict__ z_what_last,
    const float* __restrict__ Wm_wt, const float* __restrict__ bm_wt,
    const float* __restrict__ Wm_pr, const float* __restrict__ bm_pr,
    const float* __restrict__ Ws_pr, const float* __restrict__ bs_pr,
    const float* __restrict__ zw_cur, const float* __restrict__ z_pres_last,
    float* __restrict__ zwhat_cur, float* __restrict__ out_zwhat,
    float* __restrict__ out_htemp, float* __restrict__ out_zpres,
    bf16* __restrict__ rin_next, int k)
{
    __shared__ float L[615];
    int n = blockIdx.x, j = threadIdx.x;
    const float* g = gates + (size_t)n*1024;
    float ig = sigm(g[j]);
    float fg = sigm(g[256+j]);
    float gg = tanhf(g[512+j]);
    float og = sigm(g[768+j]);
    float c2 = fg*c_r[n*256+j] + ig*gg;
    float hv = og*tanhf(c2);
    out_htemp[((size_t)n*KO + k)*HIDD + j] = hv;
    L[309+j] = hv;
    L[53+j]  = h_r[n*256+j];
    if (j < 50)      L[j]  = z_what_last[((size_t)n*KO + k)*50 + j];
    else if (j < 53) L[j]  = zw_cur[n*3 + (j-50)];
    __syncthreads();
    if (j < 200) {
        int m = j >> 2, part = j & 3;
        const float* wt = Wm_wt + m*562;
        float s = 0.f;
        for (int i = part; i < 562; i += 4) {
            float v = (i < 50) ? L[i] : L[i+3];
            s = fmaf(v, wt[i], s);
        }
        s += __shfl_down(s, 2);
        s += __shfl_down(s, 1);
        if (part == 0) {
            float acc = s + bm_wt[m];
            zwhat_cur[n*50+m] = acc;
            out_zwhat[((size_t)n*KO + k)*50 + m] = acc;
            rin_next[(size_t)n*RIN_LD + 156 + m] = __float2bfloat16(acc);
            L[565+m] = acc;
        }
    }
    __syncthreads();
    if (j < 64) {
        float s1 = 0.f, s2 = 0.f;
        for (int i = j; i < 565; i += 64) {
            float v = (i < 50) ? L[565+i] : L[i];
            s1 = fmaf(v, Wm_pr[i], s1);
            s2 = fmaf(v, Ws_pr[i], s2);
        }
        #pragma unroll
        for (int off = 32; off; off >>= 1) { s1 += __shfl_down(s1,off); s2 += __shfl_down(s2,off); }
        if (j == 0) {
            float p = sigm(s1 + bm_pr[0]) * sigm(s2 + bs_pr[0]);
            out_zpres[(size_t)n*KO + k] = p * z_pres_last[(size_t)n*KO + k];
        }
    }
}

extern "C" void kernel_launch(void* const* d_in, const int* in_sizes, int n_in,
                              void* d_out, int out_size, void* d_ws, size_t ws_size,
                              hipStream_t stream) {
    (void)in_sizes; (void)n_in; (void)out_size;
    const float* img          = (const float*)d_in[0];
    const float* z_what_last  = (const float*)d_in[1];
    const float* z_where_last = (const float*)d_in[2];
    const float* z_pres_last  = (const float*)d_in[3];
    const float* hidden_last  = (const float*)d_in[4];
    const float* W_loca = (const float*)d_in[5];
    const float* b_loca = (const float*)d_in[6];
    const float* Wg     = (const float*)d_in[7];
    const float* bg     = (const float*)d_in[8];
    const float* Wih_rel = (const float*)d_in[9];
    const float* Whh_rel = (const float*)d_in[10];
    const float* bih_rel = (const float*)d_in[11];
    const float* bhh_rel = (const float*)d_in[12];
    const float* Wih_tem = (const float*)d_in[13];
    const float* Whh_tem = (const float*)d_in[14];
    const float* bih_tem = (const float*)d_in[15];
    const float* bhh_tem = (const float*)d_in[16];
    const float* Wm_wh = (const float*)d_in[17];
    const float* bm_wh = (const float*)d_in[18];
    const float* Wm_wt = (const float*)d_in[21];
    const float* bm_wt = (const float*)d_in[22];
    const float* Wm_pr = (const float*)d_in[25];
    const float* bm_pr = (const float*)d_in[26];
    const float* Ws_pr = (const float*)d_in[27];
    const float* bs_pr = (const float*)d_in[28];

    char* base_p = (char*)d_ws;
    size_t off = 0;
    auto carve = [&](size_t bytes) -> char* {
        char* r = base_p + off;
        off += (bytes + 255) & ~(size_t)255;
        return r;
    };
    bf16*  tin      = (bf16*) carve((size_t)NN*TIN_LD*2);
    float* gates    = (float*)carve((size_t)NN*1024*4);
    bf16*  W_tem    = (bf16*) carve((size_t)1024*TIN_LD*2);
    bf16*  W_rel    = (bf16*) carve((size_t)1024*RIN_LD*2);
    bf16*  Wg_bf    = (bf16*) carve((size_t)100*G1_LD*2);
    float* zwb_all  = (float*)carve((size_t)KO*NN*3*4);
    float* h_r      = (float*)carve((size_t)NN*HIDD*4);
    // zero block: c_r, zw1, zwhat1 contiguous
    float* c_r      = (float*)carve((size_t)NN*HIDD*4);
    float* zw1      = (float*)carve((size_t)NN*3*4);
    float* zwhat1   = (float*)carve((size_t)NN*50*4);
    float* zw0      = (float*)carve((size_t)NN*3*4);
    float* zwhat0   = (float*)carve((size_t)NN*50*4);
    size_t fixed_bytes = off;

    int CH = 1;
    for (int cand : {8, 4, 2}) {
        size_t need = fixed_bytes
                    + (((size_t)cand*NN*G1_LD*2 + 255) & ~(size_t)255)
                    + (((size_t)cand*NN*RIN_LD*2 + 255) & ~(size_t)255);
        if (need <= ws_size) { CH = cand; break; }
    }
    bf16* g1 = nullptr; int g1ld;
    bf16* rin;
    if (CH > 1) {
        g1   = (bf16*)carve((size_t)CH*NN*G1_LD*2);
        rin  = (bf16*)carve((size_t)CH*NN*RIN_LD*2);
        g1ld = G1_LD;
    } else {
        rin  = (bf16*)carve((size_t)NN*RIN_LD*2);
        g1   = tin;          // glimpse1 -> tin cols 0..2500; Wg pad cols (2500..2560) are zero
        g1ld = TIN_LD;
    }

    float* out        = (float*)d_out;
    float* out_zwhat  = out;
    float* out_zwhere = out + (size_t)NN*KO*50;
    float* out_zpres  = out_zwhere + (size_t)NN*KO*3;
    float* out_htemp  = out_zpres + (size_t)NN*KO;

    // ---- preamble (carry-independent) ----
    {
        int nz = NN*(HIDD + 3 + 50);   // c_r, zw1, zwhat1
        zero_f32<<<(nz+255)/256, 256, 0, stream>>>(c_r, nz);
    }
    zero_rin_carry<<<(NN*309+255)/256, 256, 0, stream>>>(rin);
    repack_w<<<((1024*RIN_LD)+255)/256, 256, 0, stream>>>(Wih_rel, 462, Whh_rel, 256, W_rel, RIN_LD, 1024);
    repack_w<<<((1024*TIN_LD)+255)/256, 256, 0, stream>>>(Wih_tem, 2862, Whh_tem, 256, W_tem, TIN_LD, 1024);
    repack_w<<<((100*G1_LD)+255)/256, 256, 0, stream>>>(Wg, 2500, nullptr, 0, Wg_bf, G1_LD, 100);
    zwb_all_v2<<<KO*NN/4, 256, 0, stream>>>(hidden_last, z_where_last, W_loca, b_loca, zwb_all);

    for (int cbase = 0; cbase < KO; cbase += CH) {
        fill_rin_static<<<(CH*NN*309+255)/256, 256, 0, stream>>>(rin, z_where_last, z_what_last, hidden_last, cbase, CH);
        glimpse_batch<<<CH*NN, 256, 0, stream>>>(img, zwb_all + (size_t)cbase*NN*3, g1, g1ld);
        // enc GEMM: 1D grid = 2 * CH*32 (multiple of 8), nxb=2
        mfma_gemm<1,1><<<2*CH*32, 256, 0, stream>>>(g1, g1ld, G1_LD, Wg_bf, G1_LD, 100, bg, nullptr, rin, RIN_LD, 2);

        for (int s = 0; s < CH; ++s) {
            int k = cbase + s;
            bf16* rin_k  = rin + (size_t)s*NN*RIN_LD;
            bf16* rin_nx = rin + (size_t)((s+1)%CH)*NN*RIN_LD;
            float* zw_cur     = (k & 1) ? zw1 : zw0;
            float* zw_prev    = (k & 1) ? zw0 : zw1;
            float* zwhat_cur  = (k & 1) ? zwhat1 : zwhat0;
            float* zwhat_prev = (k & 1) ? zwhat0 : zwhat1;

            // rel LSTM gates (ih+hh fused, K=768), 512 blocks, nxb=16
            mfma_gemm<0,0><<<512, 256, 0, stream>>>(rin_k, RIN_LD, RIN_LD, W_rel, RIN_LD, 1024, bih_rel, bhh_rel, gates, 1024, 16);
            rel_fused<<<NN, 256, 0, stream>>>(gates, h_r, c_r, z_where_last, Wm_wh, bm_wh, zw_cur, out_zwhere, rin_nx, tin, k);
            glimpse2_fused<<<NN, 256, 0, stream>>>(img, zw_cur, zw_prev, zwhat_prev, z_what_last, hidden_last, tin, k);
            // tem LSTM gates (ih+hh fused, K=3136), 512 blocks, nxb=16
            mfma_gemm<0,0><<<512, 256, 0, stream>>>(tin, TIN_LD, TIN_LD, W_tem, TIN_LD, 1024, bih_tem, bhh_tem, gates, 1024, 16);
            tem_fused<<<NN, 256, 0, stream>>>(gates, c_r, h_r, z_what_last, Wm_wt, bm_wt, Wm_pr, bm_pr, Ws_pr, bs_pr,
                                              zw_cur, z_pres_last, zwhat_cur, out_zwhat, out_htemp, out_zpres, rin_nx, k);
        }
    }
}

// Round 10
// 1318.063 us; speedup vs baseline: 1.1128x; 1.0197x over previous
//
#include <hip/hip_runtime.h>
#include <hip/hip_bf16.h>
#include <math.h>

typedef __attribute__((ext_vector_type(8))) short bf16x8;
typedef __attribute__((ext_vector_type(4))) float f32x4;
using bf16 = __hip_bfloat16;

constexpr int NN   = 2048;
constexpr int KO   = 8;
constexpr int IH   = 128, IW = 128;
constexpr int GS   = 50;
constexpr int HIDD = 256;
// rin: [enc 0..100 | zwl 100..103 | pzw 103..106 | zwhatl 106..156 | pzwhat 156..206 | hl 206..462 | h_r 462..718 | pad..768]
constexpr int RIN_LD = 768;
// tin: [g2 0..2500 | zw 2500..2503 | pzw 2503..2506 | zwhatl 2506..2556 | pzwhat 2556..2606 | hl 2606..2862 | h_r2 2862..3118 | pad..3136]
constexpr int TIN_LD = 3136;
constexpr int G1_LD  = 2560;
constexpr int GROWS  = 64;        // LDS-staged image rows for glimpse1 (32 KB)

__device__ __forceinline__ float sigm(float x) { return 1.f/(1.f+expf(-x)); }

// ================= MFMA GEMM v3 + XCD swizzle: 64x64 tile, BK=64, 2 blocks/CU ==================
template<int OUT_BF16, int RELU>
__global__ __launch_bounds__(256, 2) void mfma_gemm(
    const bf16* __restrict__ A, int lda, int Kd,
    const bf16* __restrict__ Wt, int ldw, int M,
    const float* __restrict__ b1, const float* __restrict__ b2,
    void* __restrict__ Cout, int ldc, int nxb)
{
    __shared__ bf16x8 As16[512];
    __shared__ bf16x8 Bs16[512];
    const int b    = blockIdx.x;
    const int xcd  = b & 7;
    const int t    = b >> 3;
    const int n0   = (xcd + 8*(t / nxb))*64;
    const int m0   = (t % nxb)*64;
    const int tid  = threadIdx.x;
    const int wave = tid>>6, lane = tid&63;
    const int wy   = wave>>1, wx = wave&1;

    const int row = tid>>2, part = tid&3;
    const bf16* Ap = A + (size_t)(n0+row)*lda + part*8;
    const int   wm = m0 + row;
    const bool  wok = wm < M;
    const bf16* Wp = Wt + (size_t)(wok ? wm : 0)*ldw + part*8;
    const int dst0 = ((row>>4)*2+0)*64 + part*16 + (row&15);
    const int dst1 = dst0 + 64;

    f32x4 acc[2][2] = {};
    const bf16x8 z8 = {};
    bf16x8 pa0 = *(const bf16x8*)Ap;
    bf16x8 pa1 = *(const bf16x8*)(Ap + 32);
    bf16x8 pw0 = *(const bf16x8*)Wp;
    bf16x8 pw1 = *(const bf16x8*)(Wp + 32);

    for (int k0 = 0; k0 < Kd; k0 += 64) {
        __syncthreads();
        As16[dst0] = pa0;
        As16[dst1] = pa1;
        Bs16[dst0] = wok ? pw0 : z8;
        Bs16[dst1] = wok ? pw1 : z8;
        __syncthreads();
        if (k0 + 64 < Kd) {
            pa0 = *(const bf16x8*)(Ap + k0 + 64);
            pa1 = *(const bf16x8*)(Ap + k0 + 96);
            pw0 = *(const bf16x8*)(Wp + k0 + 64);
            pw1 = *(const bf16x8*)(Wp + k0 + 96);
        }
        bf16x8 av[2][2], bv[2][2];
        #pragma unroll
        for (int i=0;i<2;i++)
            #pragma unroll
            for (int h=0;h<2;h++) av[i][h] = As16[((wy*2+i)*2+h)*64 + lane];
        #pragma unroll
        for (int j=0;j<2;j++)
            #pragma unroll
            for (int h=0;h<2;h++) bv[j][h] = Bs16[((wx*2+j)*2+h)*64 + lane];
        #pragma unroll
        for (int h=0;h<2;h++)
            #pragma unroll
            for (int i=0;i<2;i++)
                #pragma unroll
                for (int j=0;j<2;j++)
                    acc[i][j] = __builtin_amdgcn_mfma_f32_16x16x32_bf16(av[i][h], bv[j][h], acc[i][j], 0, 0, 0);
    }

    const int q = lane>>4, r = lane&15;
    #pragma unroll
    for (int j=0;j<2;j++) {
        int col = m0 + wx*32 + j*16 + r;
        if (col < M) {
            float bias = 0.f;
            if (b1) bias += b1[col];
            if (b2) bias += b2[col];
            #pragma unroll
            for (int i=0;i<2;i++) {
                #pragma unroll
                for (int reg=0;reg<4;reg++) {
                    float v = acc[i][j][reg] + bias;
                    if (RELU) v = fmaxf(v, 0.f);
                    size_t idx = (size_t)(n0 + wy*32 + i*16 + q*4 + reg)*ldc + col;
                    if (OUT_BF16) ((bf16*)Cout)[idx] = __float2bfloat16(v);
                    else          ((float*)Cout)[idx] = v;
                }
            }
        }
    }
}

// ================= glimpse point math (global-gather path) =================
__device__ __forceinline__ void glimpse_points_global(const float* __restrict__ im,
                                                      float s, float tx, float ty,
                                                      bf16* __restrict__ drow) {
    const float GXS = 2.0f/49.0f;
    const float txp = tx + 1.0f, typ = ty + 1.0f;
    for (int p2 = threadIdx.x; p2 < 1250; p2 += 256) {
        int i = p2 / 25, j = (p2 - i*25)*2;
        float gy  = fmaf((float)i, GXS, -1.0f);
        float py  = fmaf(s, gy, typ)*63.5f;
        float y0f = floorf(py); float fy = py - y0f; int y0 = (int)y0f;
        float wy0 = ((unsigned)y0     < 128u) ? (1.f - fy) : 0.f;
        float wy1 = ((unsigned)(y0+1) < 128u) ? fy         : 0.f;
        const float* r0 = im + min(max(y0,  0),127)*IW;
        const float* r1 = im + min(max(y0+1,0),127)*IW;
        float gxa = fmaf((float)j, GXS, -1.0f);
        float pxa = fmaf(s, gxa, txp)*63.5f;
        float xa0f = floorf(pxa); float fa = pxa - xa0f; int xa0 = (int)xa0f;
        float wa0 = ((unsigned)xa0     < 128u) ? (1.f - fa) : 0.f;
        float wa1 = ((unsigned)(xa0+1) < 128u) ? fa         : 0.f;
        int xa0c = min(max(xa0,  0),127), xa1c = min(max(xa0+1,0),127);
        float gxb = fmaf((float)(j+1), GXS, -1.0f);
        float pxb = fmaf(s, gxb, txp)*63.5f;
        float xb0f = floorf(pxb); float fb = pxb - xb0f; int xb0 = (int)xb0f;
        float wb0 = ((unsigned)xb0     < 128u) ? (1.f - fb) : 0.f;
        float wb1 = ((unsigned)(xb0+1) < 128u) ? fb         : 0.f;
        int xb0c = min(max(xb0,  0),127), xb1c = min(max(xb0+1,0),127);

        float va = fmaf(wy1, fmaf(wa0, r1[xa0c], wa1*r1[xa1c]),
                   wy0 *     fmaf(wa0, r0[xa0c], wa1*r0[xa1c]));
        float vb = fmaf(wy1, fmaf(wb0, r1[xb0c], wb1*r1[xb1c]),
                   wy0 *     fmaf(wb0, r0[xb0c], wb1*r0[xb1c]));

        bf16 b0 = __float2bfloat16(va), b1 = __float2bfloat16(vb);
        unsigned short u0, u1;
        __builtin_memcpy(&u0, &b0, 2); __builtin_memcpy(&u1, &b1, 2);
        *(unsigned int*)(drow + i*GS + j) = (unsigned)u0 | ((unsigned)u1 << 16);
    }
}

// ========= glimpse1 (LDS row-staged, fallback global) + rin static-col fill, fused =========
__global__ __launch_bounds__(256) void glimpse_batch(const float* __restrict__ img,
                                                     const float* __restrict__ z,
                                                     bf16* __restrict__ dst, int ldd,
                                                     bf16* __restrict__ rin,
                                                     const float* __restrict__ z_where_last,
                                                     const float* __restrict__ z_what_last,
                                                     const float* __restrict__ hidden_last,
                                                     int cbase) {
    __shared__ float rows[GROWS*IW];
    int b = blockIdx.x;
    int n = b & (NN-1);
    int sl = b >> 11;
    const float* im = img + (size_t)n*IH*IW;
    float s  = z[b*3+0];
    float tx = z[b*3+1];
    float ty = z[b*3+2];
    bf16* drow = dst + (size_t)b*ldd;

    const float GXS = 2.0f/49.0f;
    const float txp = tx + 1.0f, typ = ty + 1.0f;
    float pyA = fmaf(s, -1.f, typ)*63.5f;
    float pyB = fmaf(s,  1.f, typ)*63.5f;
    int ylo = (int)floorf(fminf(pyA, pyB));
    int yhi = (int)floorf(fmaxf(pyA, pyB)) + 1;
    ylo = min(max(ylo, 0), 127);
    yhi = min(max(yhi, 0), 127);
    int nrows = yhi - ylo + 1;

    if (nrows <= GROWS) {
        const float4* src = (const float4*)(im + ylo*IW);
        float4* d4 = (float4*)rows;
        int tot = nrows*(IW/4);
        for (int t = threadIdx.x; t < tot; t += 256) d4[t] = src[t];
        __syncthreads();
        for (int p2 = threadIdx.x; p2 < 1250; p2 += 256) {
            int i = p2 / 25, j = (p2 - i*25)*2;
            float gy  = fmaf((float)i, GXS, -1.0f);
            float py  = fmaf(s, gy, typ)*63.5f;
            float y0f = floorf(py); float fy = py - y0f; int y0 = (int)y0f;
            float wy0 = ((unsigned)y0     < 128u) ? (1.f - fy) : 0.f;
            float wy1 = ((unsigned)(y0+1) < 128u) ? fy         : 0.f;
            const float* r0 = rows + min(max(y0-ylo,   0), nrows-1)*IW;
            const float* r1 = rows + min(max(y0+1-ylo, 0), nrows-1)*IW;
            float gxa = fmaf((float)j, GXS, -1.0f);
            float pxa = fmaf(s, gxa, txp)*63.5f;
            float xa0f = floorf(pxa); float fa = pxa - xa0f; int xa0 = (int)xa0f;
            float wa0 = ((unsigned)xa0     < 128u) ? (1.f - fa) : 0.f;
            float wa1 = ((unsigned)(xa0+1) < 128u) ? fa         : 0.f;
            int xa0c = min(max(xa0,  0),127), xa1c = min(max(xa0+1,0),127);
            float gxb = fmaf((float)(j+1), GXS, -1.0f);
            float pxb = fmaf(s, gxb, txp)*63.5f;
            float xb0f = floorf(pxb); float fb = pxb - xb0f; int xb0 = (int)xb0f;
            float wb0 = ((unsigned)xb0     < 128u) ? (1.f - fb) : 0.f;
            float wb1 = ((unsigned)(xb0+1) < 128u) ? fb         : 0.f;
            int xb0c = min(max(xb0,  0),127), xb1c = min(max(xb0+1,0),127);
            float va = fmaf(wy1, fmaf(wa0, r1[xa0c], wa1*r1[xa1c]),
                       wy0 *     fmaf(wa0, r0[xa0c], wa1*r0[xa1c]));
            float vb = fmaf(wy1, fmaf(wb0, r1[xb0c], wb1*r1[xb1c]),
                       wy0 *     fmaf(wb0, r0[xb0c], wb1*r0[xb1c]));
            bf16 b0 = __float2bfloat16(va), b1 = __float2bfloat16(vb);
            unsigned short u0, u1;
            __builtin_memcpy(&u0, &b0, 2); __builtin_memcpy(&u1, &b1, 2);
            *(unsigned int*)(drow + i*GS + j) = (unsigned)u0 | ((unsigned)u1 << 16);
        }
    } else {
        glimpse_points_global(im, s, tx, ty, drow);
    }

    // fused rin static-col fill: zwl(100..103), zwhatl(106..156), hl(206..462)
    int k = cbase + sl;
    bf16* rrow = rin + (size_t)b*RIN_LD;
    for (int c = threadIdx.x; c < 309; c += 256) {
        float v; int col;
        if (c < 3)       { col = 100 + c;      v = z_where_last[((size_t)n*KO + k)*3 + c]; }
        else if (c < 53) { col = 106 + (c-3);  v = z_what_last[((size_t)n*KO + k)*50 + (c-3)]; }
        else             { col = 206 + (c-53); v = hidden_last[((size_t)n*KO + k)*HIDD + (c-53)]; }
        rrow[col] = __float2bfloat16(v);
    }
}

// ===== merged per-step kernel: rel LSTM elementwise + zw linear + glimpse2 + tin fill =====
__global__ __launch_bounds__(256) void rel_glimpse2(
    const float* __restrict__ gates, float* __restrict__ h_r, float* __restrict__ c_r,
    const float* __restrict__ z_where_last,
    const float* __restrict__ Wm_wh, const float* __restrict__ bm_wh,
    float* __restrict__ zw_cur, float* __restrict__ out_zwhere,
    bf16* __restrict__ rin_next, bf16* __restrict__ tin,
    const float* __restrict__ img,
    const float* __restrict__ zw_prev, const float* __restrict__ zwhat_prev,
    const float* __restrict__ z_what_last, const float* __restrict__ hidden_last, int k)
{
    __shared__ float hs[256];
    __shared__ float zws[3];
    int n = blockIdx.x, j = threadIdx.x;
    const float* g = gates + (size_t)n*1024;
    float ig = sigm(g[j]);
    float fg = sigm(g[256+j]);
    float gg = tanhf(g[512+j]);
    float og = sigm(g[768+j]);
    int cidx = n*256 + j;
    float c2 = fg*c_r[cidx] + ig*gg;
    float hv = og*tanhf(c2);
    c_r[cidx] = c2;
    h_r[cidx] = hv;
    hs[j] = hv;
    bf16 hb = __float2bfloat16(hv);
    rin_next[(size_t)n*RIN_LD + 462 + j] = hb;
    bf16* trow = tin + (size_t)n*TIN_LD;
    trow[2862 + j] = hb;
    __syncthreads();
    int w = j >> 6, lane = j & 63;
    if (w < 3) {
        const float* wt = Wm_wh + w*259;
        float sa = 0.f;
        for (int i = lane; i < 256; i += 64) sa = fmaf(hs[i], wt[3+i], sa);
        #pragma unroll
        for (int off = 32; off; off >>= 1) sa += __shfl_down(sa, off);
        if (lane == 0) {
            const float* zwl = z_where_last + ((size_t)n*KO + k)*3;
            float acc = bm_wh[w] + sa;
            for (int i = 0; i < 3; i++) acc = fmaf(zwl[i], wt[i], acc);
            zws[w] = acc;
            zw_cur[n*3+w] = acc;
            out_zwhere[((size_t)n*KO + k)*3 + w] = acc;
            bf16 ab = __float2bfloat16(acc);
            rin_next[(size_t)n*RIN_LD + 103 + w] = ab;
            trow[2500 + w] = ab;
        }
    }
    __syncthreads();
    float s = zws[0], tx = zws[1], ty = zws[2];
    glimpse_points_global(img + (size_t)n*IH*IW, s, tx, ty, trow);
    for (int c = 3 + j; c < 362; c += 256) {
        float v;
        if      (c <   6) v = zw_prev[n*3 + c-3];
        else if (c <  56) v = z_what_last[((size_t)n*KO + k)*50 + c-6];
        else if (c < 106) v = zwhat_prev[n*50 + c-56];
        else              v = hidden_last[((size_t)n*KO + k)*HIDD + c-106];
        trow[2500 + c] = __float2bfloat16(v);
    }
}

// ================= small / preamble kernels =================
__global__ void zero_f32(float* __restrict__ p, int n) {
    int i = blockIdx.x*blockDim.x + threadIdx.x;
    if (i < n) p[i] = 0.f;
}

__global__ void repack_w(const float* __restrict__ s1, int K1,
                         const float* __restrict__ s2, int K2,
                         bf16* __restrict__ dst, int ldd, int M) {
    int gid = blockIdx.x*blockDim.x + threadIdx.x;
    if (gid >= M*ldd) return;
    int m = gid / ldd, c = gid - m*ldd;
    float v = 0.f;
    if (c < K1)           v = s1[(size_t)m*K1 + c];
    else if (c < K1+K2)   v = s2[(size_t)m*K2 + (c-K1)];
    dst[gid] = __float2bfloat16(v);
}

__global__ __launch_bounds__(256) void zwb_all_v2(const float* __restrict__ hidden_last,
                                                  const float* __restrict__ z_where_last,
                                                  const float* __restrict__ Wl, const float* __restrict__ bl,
                                                  float* __restrict__ zwb_all) {
    __shared__ float wls[768];
    for (int i = threadIdx.x; i < 768; i += 256) wls[i] = Wl[i];
    __syncthreads();
    int wv = threadIdx.x>>6, lane = threadIdx.x&63;
    int row = blockIdx.x*4 + wv;
    int s = row >> 11, n = row & (NN-1);
    const float* hl = hidden_last + ((size_t)n*KO + s)*HIDD;
    float4 h4 = *(const float4*)(hl + lane*4);
    float s0=0.f, s1=0.f, s2=0.f;
    #pragma unroll
    for (int r4=0;r4<4;r4++) {
        float hv = ((const float*)&h4)[r4];
        int i = lane*4 + r4;
        s0 = fmaf(hv, wls[i],     s0);
        s1 = fmaf(hv, wls[256+i], s1);
        s2 = fmaf(hv, wls[512+i], s2);
    }
    #pragma unroll
    for (int off=32; off; off>>=1) {
        s0 += __shfl_down(s0,off); s1 += __shfl_down(s1,off); s2 += __shfl_down(s2,off);
    }
    if (lane == 0) {
        const float* zwl = z_where_last + ((size_t)n*KO + s)*3;
        zwb_all[row*3+0] = fmaxf(s0+bl[0],0.f) + zwl[0];
        zwb_all[row*3+1] = fmaxf(s1+bl[1],0.f) + zwl[1];
        zwb_all[row*3+2] = fmaxf(s2+bl[2],0.f) + zwl[2];
    }
}

__global__ void zero_rin_carry(bf16* __restrict__ rin0) {
    int gid = blockIdx.x*blockDim.x + threadIdx.x;
    if (gid >= NN*309) return;
    int c = gid % 309, n = gid/309;
    int col = (c < 3) ? 103+c : ((c < 53) ? 156+(c-3) : 462+(c-53));
    rin0[(size_t)n*RIN_LD + col] = __float2bfloat16(0.f);
}

// ================= tem LSTM + zwhat + pres (block per n) =================
__global__ __launch_bounds__(256) void tem_fused(
    const float* __restrict__ gates, const float* __restrict__ c_r, const float* __restrict__ h_r,
    const float* __restrict__ z_what_last,
    const float* __restrict__ Wm_wt, const float* __restrict__ bm_wt,
    const float* __restrict__ Wm_pr, const float* __restrict__ bm_pr,
    const float* __restrict__ Ws_pr, const float* __restrict__ bs_pr,
    const float* __restrict__ zw_cur, const float* __restrict__ z_pres_last,
    float* __restrict__ zwhat_cur, float* __restrict__ out_zwhat,
    float* __restrict__ out_htemp, float* __restrict__ out_zpres,
    bf16* __restrict__ rin_next, int k)
{
    __shared__ float L[615];
    int n = blockIdx.x, j = threadIdx.x;
    const float* g = gates + (size_t)n*1024;
    float ig = sigm(g[j]);
    float fg = sigm(g[256+j]);
    float gg = tanhf(g[512+j]);
    float og = sigm(g[768+j]);
    float c2 = fg*c_r[n*256+j] + ig*gg;
    float hv = og*tanhf(c2);
    out_htemp[((size_t)n*KO + k)*HIDD + j] = hv;
    L[309+j] = hv;
    L[53+j]  = h_r[n*256+j];
    if (j < 50)      L[j]  = z_what_last[((size_t)n*KO + k)*50 + j];
    else if (j < 53) L[j]  = zw_cur[n*3 + (j-50)];
    __syncthreads();
    if (j < 200) {
        int m = j >> 2, part = j & 3;
        const float* wt = Wm_wt + m*562;
        float s = 0.f;
        for (int i = part; i < 562; i += 4) {
            float v = (i < 50) ? L[i] : L[i+3];
            s = fmaf(v, wt[i], s);
        }
        s += __shfl_down(s, 2);
        s += __shfl_down(s, 1);
        if (part == 0) {
            float acc = s + bm_wt[m];
            zwhat_cur[n*50+m] = acc;
            out_zwhat[((size_t)n*KO + k)*50 + m] = acc;
            rin_next[(size_t)n*RIN_LD + 156 + m] = __float2bfloat16(acc);
            L[565+m] = acc;
        }
    }
    __syncthreads();
    if (j < 64) {
        float s1 = 0.f, s2 = 0.f;
        for (int i = j; i < 565; i += 64) {
            float v = (i < 50) ? L[565+i] : L[i];
            s1 = fmaf(v, Wm_pr[i], s1);
            s2 = fmaf(v, Ws_pr[i], s2);
        }
        #pragma unroll
        for (int off = 32; off; off >>= 1) { s1 += __shfl_down(s1,off); s2 += __shfl_down(s2,off); }
        if (j == 0) {
            float p = sigm(s1 + bm_pr[0]) * sigm(s2 + bs_pr[0]);
            out_zpres[(size_t)n*KO + k] = p * z_pres_last[(size_t)n*KO + k];
        }
    }
}

extern "C" void kernel_launch(void* const* d_in, const int* in_sizes, int n_in,
                              void* d_out, int out_size, void* d_ws, size_t ws_size,
                              hipStream_t stream) {
    (void)in_sizes; (void)n_in; (void)out_size;
    const float* img          = (const float*)d_in[0];
    const float* z_what_last  = (const float*)d_in[1];
    const float* z_where_last = (const float*)d_in[2];
    const float* z_pres_last  = (const float*)d_in[3];
    const float* hidden_last  = (const float*)d_in[4];
    const float* W_loca = (const float*)d_in[5];
    const float* b_loca = (const float*)d_in[6];
    const float* Wg     = (const float*)d_in[7];
    const float* bg     = (const float*)d_in[8];
    const float* Wih_rel = (const float*)d_in[9];
    const float* Whh_rel = (const float*)d_in[10];
    const float* bih_rel = (const float*)d_in[11];
    const float* bhh_rel = (const float*)d_in[12];
    const float* Wih_tem = (const float*)d_in[13];
    const float* Whh_tem = (const float*)d_in[14];
    const float* bih_tem = (const float*)d_in[15];
    const float* bhh_tem = (const float*)d_in[16];
    const float* Wm_wh = (const float*)d_in[17];
    const float* bm_wh = (const float*)d_in[18];
    const float* Wm_wt = (const float*)d_in[21];
    const float* bm_wt = (const float*)d_in[22];
    const float* Wm_pr = (const float*)d_in[25];
    const float* bm_pr = (const float*)d_in[26];
    const float* Ws_pr = (const float*)d_in[27];
    const float* bs_pr = (const float*)d_in[28];

    char* base_p = (char*)d_ws;
    size_t off = 0;
    auto carve = [&](size_t bytes) -> char* {
        char* r = base_p + off;
        off += (bytes + 255) & ~(size_t)255;
        return r;
    };
    bf16*  tin      = (bf16*) carve((size_t)NN*TIN_LD*2);
    float* gates    = (float*)carve((size_t)NN*1024*4);
    bf16*  W_tem    = (bf16*) carve((size_t)1024*TIN_LD*2);
    bf16*  W_rel    = (bf16*) carve((size_t)1024*RIN_LD*2);
    bf16*  Wg_bf    = (bf16*) carve((size_t)100*G1_LD*2);
    float* zwb_all  = (float*)carve((size_t)KO*NN*3*4);
    float* h_r      = (float*)carve((size_t)NN*HIDD*4);
    // zero block: c_r, zw1, zwhat1 contiguous
    float* c_r      = (float*)carve((size_t)NN*HIDD*4);
    float* zw1      = (float*)carve((size_t)NN*3*4);
    float* zwhat1   = (float*)carve((size_t)NN*50*4);
    float* zw0      = (float*)carve((size_t)NN*3*4);
    float* zwhat0   = (float*)carve((size_t)NN*50*4);
    size_t fixed_bytes = off;

    int CH = 1;
    for (int cand : {8, 4, 2}) {
        size_t need = fixed_bytes
                    + (((size_t)cand*NN*G1_LD*2 + 255) & ~(size_t)255)
                    + (((size_t)cand*NN*RIN_LD*2 + 255) & ~(size_t)255);
        if (need <= ws_size) { CH = cand; break; }
    }
    bf16* g1 = nullptr; int g1ld;
    bf16* rin;
    if (CH > 1) {
        g1   = (bf16*)carve((size_t)CH*NN*G1_LD*2);
        rin  = (bf16*)carve((size_t)CH*NN*RIN_LD*2);
        g1ld = G1_LD;
    } else {
        rin  = (bf16*)carve((size_t)NN*RIN_LD*2);
        g1   = tin;          // glimpse1 -> tin cols 0..2500; Wg pad cols (2500..2560) are zero
        g1ld = TIN_LD;
    }

    float* out        = (float*)d_out;
    float* out_zwhat  = out;
    float* out_zwhere = out + (size_t)NN*KO*50;
    float* out_zpres  = out_zwhere + (size_t)NN*KO*3;
    float* out_htemp  = out_zpres + (size_t)NN*KO;

    // ---- preamble (carry-independent) ----
    {
        int nz = NN*(HIDD + 3 + 50);   // c_r, zw1, zwhat1
        zero_f32<<<(nz+255)/256, 256, 0, stream>>>(c_r, nz);
    }
    zero_rin_carry<<<(NN*309+255)/256, 256, 0, stream>>>(rin);
    repack_w<<<((1024*RIN_LD)+255)/256, 256, 0, stream>>>(Wih_rel, 462, Whh_rel, 256, W_rel, RIN_LD, 1024);
    repack_w<<<((1024*TIN_LD)+255)/256, 256, 0, stream>>>(Wih_tem, 2862, Whh_tem, 256, W_tem, TIN_LD, 1024);
    repack_w<<<((100*G1_LD)+255)/256, 256, 0, stream>>>(Wg, 2500, nullptr, 0, Wg_bf, G1_LD, 100);
    zwb_all_v2<<<KO*NN/4, 256, 0, stream>>>(hidden_last, z_where_last, W_loca, b_loca, zwb_all);

    for (int cbase = 0; cbase < KO; cbase += CH) {
        // glimpse1 + rin static fill (fused)
        glimpse_batch<<<CH*NN, 256, 0, stream>>>(img, zwb_all + (size_t)cbase*NN*3, g1, g1ld,
                                                 rin, z_where_last, z_what_last, hidden_last, cbase);
        // enc GEMM: 1D swizzled grid, nxb=2
        mfma_gemm<1,1><<<2*CH*32, 256, 0, stream>>>(g1, g1ld, G1_LD, Wg_bf, G1_LD, 100, bg, nullptr, rin, RIN_LD, 2);

        for (int s = 0; s < CH; ++s) {
            int k = cbase + s;
            bf16* rin_k  = rin + (size_t)s*NN*RIN_LD;
            bf16* rin_nx = rin + (size_t)((s+1)%CH)*NN*RIN_LD;
            float* zw_cur     = (k & 1) ? zw1 : zw0;
            float* zw_prev    = (k & 1) ? zw0 : zw1;
            float* zwhat_cur  = (k & 1) ? zwhat1 : zwhat0;
            float* zwhat_prev = (k & 1) ? zwhat0 : zwhat1;

            // rel LSTM gates (ih+hh fused, K=768), 512 blocks, nxb=16
            mfma_gemm<0,0><<<512, 256, 0, stream>>>(rin_k, RIN_LD, RIN_LD, W_rel, RIN_LD, 1024, bih_rel, bhh_rel, gates, 1024, 16);
            // rel LSTM elementwise + zw + glimpse2 + tin fill (merged)
            rel_glimpse2<<<NN, 256, 0, stream>>>(gates, h_r, c_r, z_where_last, Wm_wh, bm_wh,
                                                 zw_cur, out_zwhere, rin_nx, tin,
                                                 img, zw_prev, zwhat_prev, z_what_last, hidden_last, k);
            // tem LSTM gates (ih+hh fused, K=3136), 512 blocks, nxb=16
            mfma_gemm<0,0><<<512, 256, 0, stream>>>(tin, TIN_LD, TIN_LD, W_tem, TIN_LD, 1024, bih_tem, bhh_tem, gates, 1024, 16);
            tem_fused<<<NN, 256, 0, stream>>>(gates, c_r, h_r, z_what_last, Wm_wt, bm_wt, Wm_pr, bm_pr, Ws_pr, bs_pr,
                                              zw_cur, z_pres_last, zwhat_cur, out_zwhat, out_htemp, out_zpres, rin_nx, k);
        }
    }
}